// Round 13
// baseline (155.525 us; speedup 1.0000x reference)
//
#include <hip/hip_runtime.h>

typedef short short8 __attribute__((ext_vector_type(8)));
typedef short short4v __attribute__((ext_vector_type(4)));
typedef float f32x4 __attribute__((ext_vector_type(4)));
typedef float float4v __attribute__((ext_vector_type(4)));
typedef int int4v __attribute__((ext_vector_type(4)));
typedef int int2v __attribute__((ext_vector_type(2)));

__device__ __forceinline__ short f2bf(float f) {
  union { float f; unsigned u; } v; v.f = f;
  unsigned r = v.u + 0x7FFFu + ((v.u >> 16) & 1u);
  return (short)(r >> 16);
}

__device__ __forceinline__ unsigned cvtpk_bf16(float lo, float hi) {
  unsigned r;
  asm("v_cvt_pk_bf16_f32 %0, %1, %2" : "=v"(r) : "v"(lo), "v"(hi));
  return r;  // lo16 = bf16(lo), hi16 = bf16(hi)
}

// async global->LDS, 16B per lane; dest must be linear (wave base + lane*16)
#define GLD16(gp, lp)                                                   \
  __builtin_amdgcn_global_load_lds(                                     \
      (const __attribute__((address_space(1))) void*)(gp),              \
      (__attribute__((address_space(3))) void*)(lp), 16, 0, 0)

// Q scale: softmax uses exp2, so fold log2(e) into the 1/sqrt(64) scale
#define QSCALE 0.18033688011112042f

// ---------------- fused fp32 -> bf16 convert (x | w_qkv | w_proj) ----------------
__global__ __launch_bounds__(256) void cvt_all(
    const float* __restrict__ x, const float* __restrict__ wq, const float* __restrict__ wp,
    short* __restrict__ xb, short* __restrict__ wqb, short* __restrict__ wpb) {
  int i = blockIdx.x * 256 + threadIdx.x;  // in float4 units; total 2097152
  const float* s; short* d; int off;
  if (i < 1048576)      { s = x;  d = xb;  off = i; }
  else if (i < 1835008) { s = wq; d = wqb; off = i - 1048576; }
  else                  { s = wp; d = wpb; off = i - 1835008; }
  float4v v = ((const float4v*)s)[off];
  short4v o;
  o.x = f2bf(v.x); o.y = f2bf(v.y); o.z = f2bf(v.z); o.w = f2bf(v.w);
  ((short4v*)d)[off] = o;
}

// ---------------- GEMM: C[M,Ncols] = A[M,1024] @ Bw[Ncols,1024]^T + bias ----------------
// Depth-2 prefetch with counted vmcnt (T4, proven R9).
template <int MODE>
__global__ __launch_bounds__(256) void gemm_bt(
    const short* __restrict__ A, const short* __restrict__ Bw,
    const float* __restrict__ bias,
    short* __restrict__ qo, short* __restrict__ ko, short* __restrict__ vto,
    float* __restrict__ outf) {
  __shared__ short As[2][128 * 64];
  __shared__ short Bs[2][128 * 64];
  const int t = threadIdx.x;
  const int lane = t & 63, wid = t >> 6;
  const int g = lane >> 4, l15 = lane & 15;
  const int wr = (wid >> 1) * 64, wc = (wid & 1) * 64;
  const int bm0 = blockIdx.y * 128, bn0 = blockIdx.x * 128;

  const int sr = t >> 3;
  const int ssub0 = t & 7;

  // LICM: swizzled fragment offsets (row&7 == l15&7 -> uniform swizzle term)
  const int swz = (l15 & 7) << 4;
  int aoff[2][4], boff[2][4];
#pragma unroll
  for (int kk = 0; kk < 2; ++kk)
#pragma unroll
    for (int f = 0; f < 4; ++f) {
      aoff[kk][f] = ((wr + f * 16 + l15) * 128 + kk * 64 + g * 16) ^ swz;
      boff[kk][f] = ((wc + f * 16 + l15) * 128 + kk * 64 + g * 16) ^ swz;
    }

  f32x4 acc[4][4] = {};

  auto stage = [&](int buf, int k0) {
#pragma unroll
    for (int i = 0; i < 4; ++i) {
      int row = i * 32 + sr;
      int s = ssub0 ^ (row & 7);
      char* ldsA = (char*)&As[buf][0] + (i * 256 + (t & ~63)) * 16;
      char* ldsB = (char*)&Bs[buf][0] + (i * 256 + (t & ~63)) * 16;
      GLD16(A + (size_t)(bm0 + row) * 1024 + k0 + s * 8, ldsA);
      GLD16(Bw + (size_t)(bn0 + row) * 1024 + k0 + s * 8, ldsB);
    }
  };

  stage(0, 0);    // prefetch K-tile 0 (8 loads)
  stage(1, 64);   // prefetch K-tile 1 (8 more; 16 in flight)
  int curOff = 0;

  for (int it = 0; it < 16; ++it) {
    // wait for THIS tile's 8 loads (oldest in FIFO); keep next tile's in flight
    if (it == 15) asm volatile("s_waitcnt vmcnt(0)" ::: "memory");
    else          asm volatile("s_waitcnt vmcnt(8)" ::: "memory");
    __builtin_amdgcn_s_barrier();          // all waves: tile `it` ready
    __builtin_amdgcn_sched_barrier(0);
    const char* AsB = (const char*)&As[0][0] + curOff;
    const char* BsB = (const char*)&Bs[0][0] + curOff;
#pragma unroll
    for (int kk = 0; kk < 2; ++kk) {
      short8 a[4], b[4];
#pragma unroll
      for (int mi = 0; mi < 4; ++mi) a[mi] = *(const short8*)(AsB + aoff[kk][mi]);
#pragma unroll
      for (int ni = 0; ni < 4; ++ni) b[ni] = *(const short8*)(BsB + boff[kk][ni]);
#pragma unroll
      for (int mi = 0; mi < 4; ++mi)
#pragma unroll
        for (int ni = 0; ni < 4; ++ni)
          acc[mi][ni] = __builtin_amdgcn_mfma_f32_16x16x32_bf16(a[mi], b[ni], acc[mi][ni], 0, 0, 0);
    }
    __builtin_amdgcn_sched_barrier(0);     // pin all reads before the barrier
    __builtin_amdgcn_s_barrier();          // all waves done reading this buffer
    __builtin_amdgcn_sched_barrier(0);     // pin stage after the barrier
    if (it + 2 < 16) stage(it & 1, (it + 2) * 64);  // (it+2)&1 == it&1
    curOff ^= 16384;  // bytes per buffer (128*64*2)
  }

  if constexpr (MODE == 0) {
    const int which = bn0 >> 10;  // block-uniform: 0=Q, 1=K, 2=V
    if (which == 2) {
      // V^T permuted store, vectorized: 4 consecutive n in-lane -> 8B stores
#pragma unroll
      for (int mi = 0; mi < 4; ++mi) {
#pragma unroll
        for (int ni = 0; ni < 4; ++ni) {
          int gcol = bn0 + wc + ni * 16 + l15;
          int w1 = gcol & 1023;
          int h = w1 >> 6, dd = w1 & 63;
          float bv = bias[gcol];
          int grow0 = bm0 + wr + mi * 16 + g * 4;
          int b_ = grow0 >> 11, n0 = grow0 & 2047;
          int bh = b_ * 16 + h;
          int nl = n0 & 63;
          // kv bit-perm [b5][b3][b2][b4][b1][b0]; n0 4-aligned -> np0 too
          int np = (n0 & ~63) | (nl & 32) | ((nl & 12) << 1) | ((nl & 16) >> 2);
          int2v pk;
          pk.x = (int)cvtpk_bf16(acc[mi][ni][0] + bv, acc[mi][ni][1] + bv);
          pk.y = (int)cvtpk_bf16(acc[mi][ni][2] + bv, acc[mi][ni][3] + bv);
          *(int2v*)(vto + ((size_t)bh * 64 + dd) * 2048 + np) = pk;
        }
      }
    } else {
      short* dst = (which == 0) ? qo : ko;
      const float sc = (which == 0) ? QSCALE : 1.0f;
#pragma unroll
      for (int mi = 0; mi < 4; ++mi) {
#pragma unroll
        for (int ni = 0; ni < 4; ++ni) {
          int gcol = bn0 + wc + ni * 16 + l15;
          int w1 = gcol & 1023;
          int h = w1 >> 6, dd = w1 & 63;
          float bv = bias[gcol];
#pragma unroll
          for (int r = 0; r < 4; ++r) {
            int grow = bm0 + wr + mi * 16 + g * 4 + r;
            int b_ = grow >> 11, n = grow & 2047;
            int bh = b_ * 16 + h;
            dst[((size_t)bh * 2048 + n) * 64 + dd] = f2bf((acc[mi][ni][r] + bv) * sc);
          }
        }
      }
    }
  } else {
#pragma unroll
    for (int mi = 0; mi < 4; ++mi) {
#pragma unroll
      for (int ni = 0; ni < 4; ++ni) {
        int gcol = bn0 + wc + ni * 16 + l15;
        float bv = bias[gcol];
#pragma unroll
        for (int r = 0; r < 4; ++r) {
          int grow = bm0 + wr + mi * 16 + g * 4 + r;
          outf[(size_t)grow * 1024 + gcol] = acc[mi][ni][r] + bv;
        }
      }
    }
  }
}

// ---------------- flash attention: barrier-free 1-wave blocks ----------------
// Each block = ONE wave owning 32 q-rows. K is read DIRECTLY from global
// (L2-resident via XCD affinity bh=bid&31) into ping-ponged reg sets, one
// tile ahead (compiler-tracked deps). V is staged into PRIVATE per-wave LDS
// (2x8KB double buffer) via GLD16 with counted-vmcnt self-pacing. ZERO
// s_barrier: waves drift freely; rendezvous idle (R9-R12: ~60% all-pipes
// idle at lockstep 4-wave blocks) is eliminated.
// FIFO (order pinned by sched_barrier fences): prologue [V0:8, V1:8, K0:8];
// per tile [K(t+1):8 ... V(t+2):8] -> after-V(t) = 16 -> vmcnt(16) at top.
// Peeled: t=30 no V-stage; t=31 vmcnt(0), no K.
__global__ __launch_bounds__(64, 2) void attn_fused(
    const short* __restrict__ Qg, const short* __restrict__ Kg,
    const short* __restrict__ Vtg, short* __restrict__ AO) {
  __shared__ short Vs[2][64 * 64];  // 2 x 8KB, private to this wave
  const int bid = blockIdx.x;
  const int bh = bid & 31, qt = bid >> 5;
  const int t = threadIdx.x;        // 0..63 (one wave)
  const int g = t >> 4, l15 = t & 15;
  const int q0w = qt * 32;
  const short* qb = Qg + ((size_t)bh * 2048 + q0w) * 64;
  const short* kb = Kg + (size_t)bh * 2048 * 64;
  const short* vb = Vtg + (size_t)bh * 64 * 2048;

  // V staging: linear LDS dest, pre-swizzled global source (rule 21).
  // chunk c = i*64 + t -> row = i*8 + (t>>3), sub = t&7; row&7 == t>>3.
  const int srow = t >> 3;
  const int ssub = (t & 7) ^ srow;
  const short* vsrc0 = vb + (size_t)srow * 2048 + ssub * 8;

  // swizzled V fragment offsets ([64 d][64 kv] tile, 128B rows)
  const int swz = (l15 & 7) << 4;
  int foff[2][4];
#pragma unroll
  for (int kk = 0; kk < 2; ++kk)
#pragma unroll
    for (int f = 0; f < 4; ++f)
      foff[kk][f] = ((f * 16 + l15) * 128 + kk * 64 + g * 16) ^ swz;

  short8 bq[2][2];
#pragma unroll
  for (int qf = 0; qf < 2; ++qf)
#pragma unroll
    for (int kk = 0; kk < 2; ++kk)
      bq[qf][kk] = *(const short8*)(qb + (qf * 16 + l15) * 64 + kk * 32 + g * 8);

  auto stageV = [&](int buf, int p) {
    const int nn = p * 64;
    char* lds = (char*)&Vs[buf][0];
#pragma unroll
    for (int i = 0; i < 8; ++i)
      GLD16(vsrc0 + (size_t)(i * 8) * 2048 + nn, lds + i * 1024);
  };

  // K fragments direct from global: A-operand rows kv=kf*16+l15, d-elems
  // kk*32+g*8 (coalesced: 16 rows x 128B contiguous per instr).
  auto loadK = [&](short8 (&ak)[2][4], int p) {
    const short* kp = kb + (size_t)(p * 64) * 64;
#pragma unroll
    for (int kk = 0; kk < 2; ++kk)
#pragma unroll
      for (int kf = 0; kf < 4; ++kf)
        ak[kk][kf] = *(const short8*)(kp + (kf * 16 + l15) * 64 + kk * 32 + g * 8);
  };

  f32x4 acc[2][4] = {};
  float mrun[2] = {-3.0e38f, -3.0e38f}, lrun[2] = {0.f, 0.f};
  short8 akA[2][4], akB[2][4];

  // prologue: FIFO order [V0, V1, K0] (fenced)
  stageV(0, 0);
  stageV(1, 1);
  __builtin_amdgcn_sched_barrier(0);
  loadK(akA, 0);
  __builtin_amdgcn_sched_barrier(0);

  auto body = [&](short8 (&cur)[2][4], short8 (&nxt)[2][4], int p,
                  bool doK, bool doV, bool last) {
    if (last) asm volatile("s_waitcnt vmcnt(0)" ::: "memory");
    else      asm volatile("s_waitcnt vmcnt(16)" ::: "memory");  // V(p) landed
    __builtin_amdgcn_sched_barrier(0);
    if (doK) loadK(nxt, p + 1);   // prefetch next K tile into spare regs
    __builtin_amdgcn_sched_barrier(0);
    const char* VsB = (const char*)&Vs[p & 1][0];

    // S^T[kv][q]: s[qf][kf], kv = kf*16 + g*4 + r, q = qf*16 + l15
    f32x4 s[2][4] = {};
#pragma unroll
    for (int kk = 0; kk < 2; ++kk)
#pragma unroll
      for (int kf = 0; kf < 4; ++kf)
#pragma unroll
        for (int qf = 0; qf < 2; ++qf)
          s[qf][kf] = __builtin_amdgcn_mfma_f32_16x16x32_bf16(cur[kk][kf], bq[qf][kk], s[qf][kf], 0, 0, 0);

    // tile max per qf
    float pm[2];
#pragma unroll
    for (int qf = 0; qf < 2; ++qf) {
      float m0 = fmaxf(s[qf][0][0], s[qf][0][1]);
      m0 = fmaxf(fmaxf(m0, s[qf][0][2]), s[qf][0][3]);
#pragma unroll
      for (int kf = 1; kf < 4; ++kf) {
        m0 = fmaxf(fmaxf(m0, s[qf][kf][0]), s[qf][kf][1]);
        m0 = fmaxf(fmaxf(m0, s[qf][kf][2]), s[qf][kf][3]);
      }
      float x = fmaxf(m0, __shfl_xor(m0, 16));
      pm[qf] = fmaxf(x, __shfl_xor(x, 32));
    }

    // defer-max (T13)
    if (!__all((pm[0] - mrun[0] <= 8.f) && (pm[1] - mrun[1] <= 8.f))) {
#pragma unroll
      for (int qf = 0; qf < 2; ++qf) {
        float mn = fmaxf(mrun[qf], pm[qf]);
        float alpha = __builtin_amdgcn_exp2f(mrun[qf] - mn);
        mrun[qf] = mn;
        lrun[qf] *= alpha;
#pragma unroll
        for (int df = 0; df < 4; ++df)
#pragma unroll
          for (int r = 0; r < 4; ++r) acc[qf][df][r] *= alpha;
      }
    }

    // P = exp2(S - m), row sums, pack to bf16 pairs (lane-local)
    unsigned wpk[2][4][2];
#pragma unroll
    for (int qf = 0; qf < 2; ++qf) {
      float rs = 0.f;
      float pp[4][4];
#pragma unroll
      for (int kf = 0; kf < 4; ++kf)
#pragma unroll
        for (int r = 0; r < 4; ++r) {
          pp[kf][r] = __builtin_amdgcn_exp2f(s[qf][kf][r] - mrun[qf]);
          rs += pp[kf][r];
        }
      rs += __shfl_xor(rs, 16);
      rs += __shfl_xor(rs, 32);
      lrun[qf] += rs;
#pragma unroll
      for (int kf = 0; kf < 4; ++kf)
#pragma unroll
        for (int h = 0; h < 2; ++h)
          wpk[qf][kf][h] = cvtpk_bf16(pp[kf][2 * h], pp[kf][2 * h + 1]);
    }

    // O^T += V^T_perm @ P^T — B operand is the lane's own packed words
#pragma unroll
    for (int kk = 0; kk < 2; ++kk) {
      short8 av[4];
#pragma unroll
      for (int df = 0; df < 4; ++df) av[df] = *(const short8*)(VsB + foff[kk][df]);
#pragma unroll
      for (int qf = 0; qf < 2; ++qf) {
        union { int4v i; short8 s; } pv;
        pv.i[0] = (int)wpk[qf][2 * kk][0];
        pv.i[1] = (int)wpk[qf][2 * kk][1];
        pv.i[2] = (int)wpk[qf][2 * kk + 1][0];
        pv.i[3] = (int)wpk[qf][2 * kk + 1][1];
#pragma unroll
        for (int df = 0; df < 4; ++df)
          acc[qf][df] = __builtin_amdgcn_mfma_f32_16x16x32_bf16(av[df], pv.s, acc[qf][df], 0, 0, 0);
      }
    }

    // all V reads of this buffer consumed -> safe to overwrite (same wave)
    asm volatile("s_waitcnt lgkmcnt(0)" ::: "memory");
    __builtin_amdgcn_sched_barrier(0);
    if (doV) stageV(p & 1, p + 2);  // (p+2)&1 == p&1
    __builtin_amdgcn_sched_barrier(0);
  };

  for (int it2 = 0; it2 < 15; ++it2) {
    body(akA, akB, 2 * it2,     true, true, false);
    body(akB, akA, 2 * it2 + 1, true, true, false);
  }
  body(akA, akB, 30, true,  false, false);  // K(31) prefetch, no V(32)
  body(akB, akA, 31, false, false, true);   // vmcnt(0), nothing issued

  // O^T fragments: d = df*16 + g*4 + r, q = q0w + qf*16 + l15
  const int b_ = bh >> 4, h = bh & 15;
#pragma unroll
  for (int qf = 0; qf < 2; ++qf) {
    const float inv = 1.0f / lrun[qf];
    short* outp = AO + ((size_t)b_ * 2048 + q0w + qf * 16 + l15) * 1024 + h * 64 + g * 4;
#pragma unroll
    for (int df = 0; df < 4; ++df) {
      short4v o;
#pragma unroll
      for (int r = 0; r < 4; ++r) o[r] = f2bf(acc[qf][df][r] * inv);
      *(short4v*)(outp + df * 16) = o;
    }
  }
}

// ---------------- launch ----------------
extern "C" void kernel_launch(void* const* d_in, const int* in_sizes, int n_in,
                              void* d_out, int out_size, void* d_ws, size_t ws_size,
                              hipStream_t stream) {
  const float* x = (const float*)d_in[0];
  const float* w_qkv = (const float*)d_in[1];
  const float* b_qkv = (const float*)d_in[2];
  const float* w_proj = (const float*)d_in[3];
  const float* b_proj = (const float*)d_in[4];
  float* out = (float*)d_out;
  char* ws = (char*)d_ws;

  short* xb    = (short*)(ws + (size_t)0);
  short* wqkvb = (short*)(ws + ((size_t)8 << 20));
  short* wprojb= (short*)(ws + ((size_t)14 << 20));
  short* qb    = (short*)(ws + ((size_t)16 << 20));
  short* kb    = (short*)(ws + ((size_t)24 << 20));
  short* vtb   = (short*)(ws + ((size_t)32 << 20));
  short* aob   = (short*)(ws + ((size_t)40 << 20));

  cvt_all<<<8192, 256, 0, stream>>>(x, w_qkv, w_proj, xb, wqkvb, wprojb);
  gemm_bt<0><<<dim3(24, 32), 256, 0, stream>>>(xb, wqkvb, b_qkv, qb, kb, vtb, nullptr);
  attn_fused<<<2048, 64, 0, stream>>>(qb, kb, vtb, aob);
  gemm_bt<1><<<dim3(8, 32), 256, 0, stream>>>(aob, wprojb, b_proj, nullptr, nullptr, nullptr, out);
}

// Round 14
// 115.659 us; speedup vs baseline: 1.3447x; 1.3447x over previous
//
#include <hip/hip_runtime.h>

typedef short short8 __attribute__((ext_vector_type(8)));
typedef short short4v __attribute__((ext_vector_type(4)));
typedef float f32x4 __attribute__((ext_vector_type(4)));
typedef float float4v __attribute__((ext_vector_type(4)));
typedef int int4v __attribute__((ext_vector_type(4)));
typedef int int2v __attribute__((ext_vector_type(2)));

__device__ __forceinline__ short f2bf(float f) {
  union { float f; unsigned u; } v; v.f = f;
  unsigned r = v.u + 0x7FFFu + ((v.u >> 16) & 1u);
  return (short)(r >> 16);
}

__device__ __forceinline__ unsigned cvtpk_bf16(float lo, float hi) {
  unsigned r;
  asm("v_cvt_pk_bf16_f32 %0, %1, %2" : "=v"(r) : "v"(lo), "v"(hi));
  return r;  // lo16 = bf16(lo), hi16 = bf16(hi)
}

// async global->LDS, 16B per lane; dest must be linear (wave base + lane*16)
#define GLD16(gp, lp)                                                   \
  __builtin_amdgcn_global_load_lds(                                     \
      (const __attribute__((address_space(1))) void*)(gp),              \
      (__attribute__((address_space(3))) void*)(lp), 16, 0, 0)

// Q scale: softmax uses exp2, so fold log2(e) into the 1/sqrt(64) scale
#define QSCALE 0.18033688011112042f

// ---------------- fused fp32 -> bf16 convert (x | w_qkv | w_proj) ----------------
__global__ __launch_bounds__(256) void cvt_all(
    const float* __restrict__ x, const float* __restrict__ wq, const float* __restrict__ wp,
    short* __restrict__ xb, short* __restrict__ wqb, short* __restrict__ wpb) {
  int i = blockIdx.x * 256 + threadIdx.x;  // in float4 units; total 2097152
  const float* s; short* d; int off;
  if (i < 1048576)      { s = x;  d = xb;  off = i; }
  else if (i < 1835008) { s = wq; d = wqb; off = i - 1048576; }
  else                  { s = wp; d = wpb; off = i - 1835008; }
  float4v v = ((const float4v*)s)[off];
  short4v o;
  o.x = f2bf(v.x); o.y = f2bf(v.y); o.z = f2bf(v.z); o.w = f2bf(v.w);
  ((short4v*)d)[off] = o;
}

// ---------------- GEMM: C[M,Ncols] = A[M,1024] @ Bw[Ncols,1024]^T + bias ----------------
// BK=32, 3 LDS slots (48KB -> 3 blocks/CU), depth-3 prefetch with counted
// vmcnt, XCD-affine flat-grid decode (4 A-panels = 1MB L2-resident per XCD).
// qkv grid = 768 = exactly 3/CU (single round, no tail).
// 64B-row swizzle: read chunk g ^ ((l15>>1)&3); source pre-swizzled with
// (t&3)^((t>>3)&3). Bank map: 2-way max (free, m136).
template <int MODE>
__global__ __launch_bounds__(256, 3) void gemm_bt(
    const short* __restrict__ A, const short* __restrict__ Bw,
    const float* __restrict__ bias,
    short* __restrict__ qo, short* __restrict__ ko, short* __restrict__ vto,
    float* __restrict__ outf) {
  __shared__ short As[3][128 * 32];  // 8KB per slot
  __shared__ short Bs[3][128 * 32];
  const int t = threadIdx.x;
  const int lane = t & 63, wid = t >> 6;
  const int g = lane >> 4, l15 = lane & 15;
  const int wr = (wid >> 1) * 64, wc = (wid & 1) * 64;
  // XCD-affine decode: bid = bn*32 + sub*8 + xcd -> bm = xcd*4 + sub
  const int bid = blockIdx.x;
  const int bm0 = ((bid & 7) * 4 + ((bid >> 3) & 3)) * 128;
  const int bn0 = (bid >> 5) * 128;

  // staging geometry (per 64-row half i): row = i*64 + (t>>2), chunk c = t&3,
  // source chunk = c ^ p(row), p(row) = (row>>1)&3 = (t>>3)&3
  const int sr = t >> 2;
  const int csrc = (t & 3) ^ ((t >> 3) & 3);

  // fragment offsets: row*64B + (g ^ ((l15>>1)&3))*16
  const int gx = (g ^ ((l15 >> 1) & 3)) << 4;
  int aoff[4], boff[4];
#pragma unroll
  for (int f = 0; f < 4; ++f) {
    aoff[f] = (wr + f * 16 + l15) * 64 + gx;
    boff[f] = (wc + f * 16 + l15) * 64 + gx;
  }

  f32x4 acc[4][4] = {};

  auto stage = [&](int offB, int k0) {
#pragma unroll
    for (int i = 0; i < 2; ++i) {
      int row = i * 64 + sr;
      char* ldsA = (char*)&As[0][0] + offB + (i * 256 + (t & ~63)) * 16;
      char* ldsB = (char*)&Bs[0][0] + offB + (i * 256 + (t & ~63)) * 16;
      GLD16(A + (size_t)(bm0 + row) * 1024 + k0 + csrc * 8, ldsA);
      GLD16(Bw + (size_t)(bn0 + row) * 1024 + k0 + csrc * 8, ldsB);
    }
  };

  stage(0, 0);         // slot0: tile 0 (4 loads)
  stage(8192, 32);     // slot1: tile 1 (8 in flight)
  stage(16384, 64);    // slot2: tile 2 (12 in flight)
  int off = 0;

  for (int it = 0; it < 32; ++it) {
    // oldest 4 = this tile; keep the two prefetched tiles in flight
    if (it < 30)       asm volatile("s_waitcnt vmcnt(8)" ::: "memory");
    else if (it == 30) asm volatile("s_waitcnt vmcnt(4)" ::: "memory");
    else               asm volatile("s_waitcnt vmcnt(0)" ::: "memory");
    __builtin_amdgcn_s_barrier();          // all waves: tile `it` ready
    __builtin_amdgcn_sched_barrier(0);
    const char* AsB = (const char*)&As[0][0] + off;
    const char* BsB = (const char*)&Bs[0][0] + off;
    short8 a[4], b[4];
#pragma unroll
    for (int mi = 0; mi < 4; ++mi) a[mi] = *(const short8*)(AsB + aoff[mi]);
#pragma unroll
    for (int ni = 0; ni < 4; ++ni) b[ni] = *(const short8*)(BsB + boff[ni]);
#pragma unroll
    for (int mi = 0; mi < 4; ++mi)
#pragma unroll
      for (int ni = 0; ni < 4; ++ni)
        acc[mi][ni] = __builtin_amdgcn_mfma_f32_16x16x32_bf16(a[mi], b[ni], acc[mi][ni], 0, 0, 0);
    __builtin_amdgcn_sched_barrier(0);     // pin all reads before the barrier
    __builtin_amdgcn_s_barrier();          // all waves done reading this slot
    __builtin_amdgcn_sched_barrier(0);     // pin stage after the barrier
    if (it + 3 < 32) stage(off, (it + 3) * 32);  // (it+3)%3 == it%3 -> same slot
    off = (off == 16384) ? 0 : off + 8192;
  }

  if constexpr (MODE == 0) {
    const int which = bn0 >> 10;  // block-uniform: 0=Q, 1=K, 2=V
    if (which == 2) {
      // V^T permuted store, vectorized: 4 consecutive n in-lane -> 8B stores
#pragma unroll
      for (int mi = 0; mi < 4; ++mi) {
#pragma unroll
        for (int ni = 0; ni < 4; ++ni) {
          int gcol = bn0 + wc + ni * 16 + l15;
          int w1 = gcol & 1023;
          int h = w1 >> 6, dd = w1 & 63;
          float bv = bias[gcol];
          int grow0 = bm0 + wr + mi * 16 + g * 4;
          int b_ = grow0 >> 11, n0 = grow0 & 2047;
          int bh = b_ * 16 + h;
          int nl = n0 & 63;
          // kv bit-perm [b5][b3][b2][b4][b1][b0]; n0 4-aligned -> np0 too
          int np = (n0 & ~63) | (nl & 32) | ((nl & 12) << 1) | ((nl & 16) >> 2);
          int2v pk;
          pk.x = (int)cvtpk_bf16(acc[mi][ni][0] + bv, acc[mi][ni][1] + bv);
          pk.y = (int)cvtpk_bf16(acc[mi][ni][2] + bv, acc[mi][ni][3] + bv);
          *(int2v*)(vto + ((size_t)bh * 64 + dd) * 2048 + np) = pk;
        }
      }
    } else {
      short* dst = (which == 0) ? qo : ko;
      const float sc = (which == 0) ? QSCALE : 1.0f;
#pragma unroll
      for (int mi = 0; mi < 4; ++mi) {
#pragma unroll
        for (int ni = 0; ni < 4; ++ni) {
          int gcol = bn0 + wc + ni * 16 + l15;
          int w1 = gcol & 1023;
          int h = w1 >> 6, dd = w1 & 63;
          float bv = bias[gcol];
#pragma unroll
          for (int r = 0; r < 4; ++r) {
            int grow = bm0 + wr + mi * 16 + g * 4 + r;
            int b_ = grow >> 11, n = grow & 2047;
            int bh = b_ * 16 + h;
            dst[((size_t)bh * 2048 + n) * 64 + dd] = f2bf((acc[mi][ni][r] + bv) * sc);
          }
        }
      }
    }
  } else {
#pragma unroll
    for (int mi = 0; mi < 4; ++mi) {
#pragma unroll
      for (int ni = 0; ni < 4; ++ni) {
        int gcol = bn0 + wc + ni * 16 + l15;
        float bv = bias[gcol];
#pragma unroll
        for (int r = 0; r < 4; ++r) {
          int grow = bm0 + wr + mi * 16 + g * 4 + r;
          outf[(size_t)grow * 1024 + gcol] = acc[mi][ni][r] + bv;
        }
      }
    }
  }
}

// ---------------- flash attention, swapped-operand, zero-shuffle PV ----------------
// Exact R10 structure (proven 58.7us): 4 waves x 32 q-rows, grid 512, 2
// blocks/CU, XCD-affine bh=bid&31, 2 sub-tiles per counted-vmcnt phase.
// Abandoned variants (do not retry): R8 16-rows/wave (DS 2x), R11 3-slot
// deferred pipeline (NaN), R12 setprio (null), R13 barrier-free 1-wave (93us).
__global__ __launch_bounds__(256, 2) void attn_fused(
    const short* __restrict__ Qg, const short* __restrict__ Kg,
    const short* __restrict__ Vtg, short* __restrict__ AO) {
  __shared__ short Ks[4][64 * 64];  // slot = buf*2 + sub, 8KB each
  __shared__ short Vs[4][64 * 64];
  const int bid = blockIdx.x;
  const int bh = bid & 31, qt = bid >> 5;
  const int t = threadIdx.x, wid = t >> 6, lane = t & 63;
  const int g = lane >> 4, l15 = lane & 15;
  const int q0w = qt * 128 + wid * 32;
  const short* qb = Qg + ((size_t)bh * 2048 + q0w) * 64;
  const short* kb = Kg + (size_t)bh * 2048 * 64;
  const short* vb = Vtg + (size_t)bh * 64 * 2048;

  // staging: linear LDS dest, pre-swizzled global source (rule 21)
  const int srow = t >> 3;
  const int ssub = (t & 7) ^ (srow & 7);
  const short* ksrc0 = kb + srow * 64 + ssub * 8;
  const short* vsrc0 = vb + (size_t)srow * 2048 + ssub * 8;

  // LICM: swizzled fragment offsets, shared by K and V reads
  const int swz = (l15 & 7) << 4;
  int foff[2][4];
#pragma unroll
  for (int kk = 0; kk < 2; ++kk)
#pragma unroll
    for (int f = 0; f < 4; ++f)
      foff[kk][f] = ((f * 16 + l15) * 128 + kk * 64 + g * 16) ^ swz;

  short8 bq[2][2];
#pragma unroll
  for (int qf = 0; qf < 2; ++qf)
#pragma unroll
    for (int kk = 0; kk < 2; ++kk)
      bq[qf][kk] = *(const short8*)(qb + (qf * 16 + l15) * 64 + kk * 32 + g * 8);

  // stage one phase = 2 sub-tiles (8 GLD16/thread)
  auto stageP = [&](int buf, int p) {
    const int n0 = p * 128;
#pragma unroll
    for (int sub = 0; sub < 2; ++sub) {
      const int nn = n0 + sub * 64;
      char* ldsK = (char*)&Ks[buf * 2 + sub][0] + wid * 1024;
      char* ldsV = (char*)&Vs[buf * 2 + sub][0] + wid * 1024;
#pragma unroll
      for (int i = 0; i < 2; ++i) {
        GLD16(ksrc0 + (size_t)(nn + i * 32) * 64, ldsK + i * 4096);
        GLD16(vsrc0 + (size_t)i * 32 * 2048 + nn, ldsV + i * 4096);
      }
    }
  };

  stageP(0, 0);  // 8 loads
  stageP(1, 1);  // 16 in flight

  f32x4 acc[2][4] = {};
  float mrun[2] = {-3.0e38f, -3.0e38f}, lrun[2] = {0.f, 0.f};

  for (int p = 0; p < 16; ++p) {
    // oldest 8 loads = this phase's 2 sub-tiles; keep next phase's in flight
    if (p == 15) asm volatile("s_waitcnt vmcnt(0)" ::: "memory");
    else         asm volatile("s_waitcnt vmcnt(8)" ::: "memory");
    __builtin_amdgcn_s_barrier();
    __builtin_amdgcn_sched_barrier(0);
    const int buf = p & 1;

#pragma unroll
    for (int sub = 0; sub < 2; ++sub) {
      const char* KsB = (const char*)&Ks[buf * 2 + sub][0];
      const char* VsB = (const char*)&Vs[buf * 2 + sub][0];

      // S^T[kv][q]: s[qf][kf], kv = kf*16 + g*4 + r, q = qf*16 + l15
      f32x4 s[2][4] = {};
#pragma unroll
      for (int kk = 0; kk < 2; ++kk) {
        short8 ak[4];
#pragma unroll
        for (int kf = 0; kf < 4; ++kf) ak[kf] = *(const short8*)(KsB + foff[kk][kf]);
#pragma unroll
        for (int kf = 0; kf < 4; ++kf)
#pragma unroll
          for (int qf = 0; qf < 2; ++qf)
            s[qf][kf] = __builtin_amdgcn_mfma_f32_16x16x32_bf16(ak[kf], bq[qf][kk], s[qf][kf], 0, 0, 0);
      }

      // tile max per qf
      float pm[2];
#pragma unroll
      for (int qf = 0; qf < 2; ++qf) {
        float m0 = fmaxf(s[qf][0][0], s[qf][0][1]);
        m0 = fmaxf(fmaxf(m0, s[qf][0][2]), s[qf][0][3]);
#pragma unroll
        for (int kf = 1; kf < 4; ++kf) {
          m0 = fmaxf(fmaxf(m0, s[qf][kf][0]), s[qf][kf][1]);
          m0 = fmaxf(fmaxf(m0, s[qf][kf][2]), s[qf][kf][3]);
        }
        float x = fmaxf(m0, __shfl_xor(m0, 16));
        pm[qf] = fmaxf(x, __shfl_xor(x, 32));
      }

      // defer-max (T13)
      if (!__all((pm[0] - mrun[0] <= 8.f) && (pm[1] - mrun[1] <= 8.f))) {
#pragma unroll
        for (int qf = 0; qf < 2; ++qf) {
          float mn = fmaxf(mrun[qf], pm[qf]);
          float alpha = __builtin_amdgcn_exp2f(mrun[qf] - mn);
          mrun[qf] = mn;
          lrun[qf] *= alpha;
#pragma unroll
          for (int df = 0; df < 4; ++df)
#pragma unroll
            for (int r = 0; r < 4; ++r) acc[qf][df][r] *= alpha;
        }
      }

      // P = exp2(S - m), row sums, pack to bf16 pairs (lane-local)
      unsigned wpk[2][4][2];
#pragma unroll
      for (int qf = 0; qf < 2; ++qf) {
        float rs = 0.f;
        float pp[4][4];
#pragma unroll
        for (int kf = 0; kf < 4; ++kf)
#pragma unroll
          for (int r = 0; r < 4; ++r) {
            pp[kf][r] = __builtin_amdgcn_exp2f(s[qf][kf][r] - mrun[qf]);
            rs += pp[kf][r];
          }
        rs += __shfl_xor(rs, 16);
        rs += __shfl_xor(rs, 32);
        lrun[qf] += rs;
#pragma unroll
        for (int kf = 0; kf < 4; ++kf)
#pragma unroll
          for (int h = 0; h < 2; ++h)
            wpk[qf][kf][h] = cvtpk_bf16(pp[kf][2 * h], pp[kf][2 * h + 1]);
      }

      // O^T += V^T_perm @ P^T — B operand is the lane's own packed words
#pragma unroll
      for (int kk = 0; kk < 2; ++kk) {
        short8 av[4];
#pragma unroll
        for (int df = 0; df < 4; ++df) av[df] = *(const short8*)(VsB + foff[kk][df]);
#pragma unroll
        for (int qf = 0; qf < 2; ++qf) {
          union { int4v i; short8 s; } pv;
          pv.i[0] = (int)wpk[qf][2 * kk][0];
          pv.i[1] = (int)wpk[qf][2 * kk][1];
          pv.i[2] = (int)wpk[qf][2 * kk + 1][0];
          pv.i[3] = (int)wpk[qf][2 * kk + 1][1];
#pragma unroll
          for (int df = 0; df < 4; ++df)
            acc[qf][df] = __builtin_amdgcn_mfma_f32_16x16x32_bf16(av[df], pv.s, acc[qf][df], 0, 0, 0);
        }
      }
    }

    __builtin_amdgcn_sched_barrier(0);  // pin reads before the barrier
    __builtin_amdgcn_s_barrier();       // all waves done reading this buf
    __builtin_amdgcn_sched_barrier(0);  // pin stage after the barrier
    if (p + 2 < 16) stageP(buf, p + 2);
  }

  // O^T fragments: d = df*16 + g*4 + r, q = q0w + qf*16 + l15
  const int b_ = bh >> 4, h = bh & 15;
#pragma unroll
  for (int qf = 0; qf < 2; ++qf) {
    const float inv = 1.0f / lrun[qf];
    short* outp = AO + ((size_t)b_ * 2048 + q0w + qf * 16 + l15) * 1024 + h * 64 + g * 4;
#pragma unroll
    for (int df = 0; df < 4; ++df) {
      short4v o;
#pragma unroll
      for (int r = 0; r < 4; ++r) o[r] = f2bf(acc[qf][df][r] * inv);
      *(short4v*)(outp + df * 16) = o;
    }
  }
}

// ---------------- launch ----------------
extern "C" void kernel_launch(void* const* d_in, const int* in_sizes, int n_in,
                              void* d_out, int out_size, void* d_ws, size_t ws_size,
                              hipStream_t stream) {
  const float* x = (const float*)d_in[0];
  const float* w_qkv = (const float*)d_in[1];
  const float* b_qkv = (const float*)d_in[2];
  const float* w_proj = (const float*)d_in[3];
  const float* b_proj = (const float*)d_in[4];
  float* out = (float*)d_out;
  char* ws = (char*)d_ws;

  short* xb    = (short*)(ws + (size_t)0);
  short* wqkvb = (short*)(ws + ((size_t)8 << 20));
  short* wprojb= (short*)(ws + ((size_t)14 << 20));
  short* qb    = (short*)(ws + ((size_t)16 << 20));
  short* kb    = (short*)(ws + ((size_t)24 << 20));
  short* vtb   = (short*)(ws + ((size_t)32 << 20));
  short* aob   = (short*)(ws + ((size_t)40 << 20));

  cvt_all<<<8192, 256, 0, stream>>>(x, w_qkv, w_proj, xb, wqkvb, wprojb);
  gemm_bt<0><<<768, 256, 0, stream>>>(xb, wqkvb, b_qkv, qb, kb, vtb, nullptr);
  attn_fused<<<512, 256, 0, stream>>>(qb, kb, vtb, aob);
  gemm_bt<1><<<256, 256, 0, stream>>>(aob, wprojb, b_proj, nullptr, nullptr, nullptr, out);
}